// Round 1
// baseline (223.036 us; speedup 1.0000x reference)
//
#include <hip/hip_runtime.h>

// RoPE: out[b,s,2k]   = cos(a)*x[b,s,2k] - sin(a)*x[b,s,2k+1]
//       out[b,s,2k+1] = sin(a)*x[b,s,2k] + cos(a)*x[b,s,2k+1]
// with a = pos[s] * theta^(-2k/D).  B=8, S=4096, D=1024, theta=1e4.
//
// Memory-bound streaming op. Ideal traffic 134 MB read + 134 MB write
// = 268 MB -> ~41 us at the 6.6 TB/s measured-achievable ceiling.
//
// Round-5 restructure: trig depends only on (s,k), not b. One thread now
// computes 4 angle pairs ONCE and applies them to all 8 batches:
//   thread (s,j) handles f32x4 elements j and j+128 of row s, for b=0..7.
//   -> 9 transcendentals per 512 B (was 7 per 32 B: 18x less trans work),
//   16 independent nontemporal loads/stores per thread for MLP,
//   grid = 2048 blocks (8/CU, per G11 for memory-bound streaming).
// Wave coalescing: lanes 0..63 share s and span j=0..63 (or 64..127), so
// each global_load_dwordx4 covers a contiguous, aligned 1024 B segment.
//
// Frequency relations (exact single multiplies, one v_exp_f32 per thread):
//   f(k+1)   = f(k) * theta^(-2/D)   = f(k) * 0.98217188
//   f(k+256) = f(k) * theta^(-1/2)   = f(k) * 0.01        (D=1024)
// v_sin/v_cos take REVOLUTIONS; angle computed directly in revolutions
// (divide by 2pi folded into the exp2 argument), reduced by v_fract
// (exact: period is 1 revolution).

typedef float f32x4 __attribute__((ext_vector_type(4)));

#define B_DIM   8
#define S_DIM   4096
#define D_DIM   1024
#define D4      (D_DIM / 4)          // 256 f32x4 per row
#define HALF    (D4 / 2)             // 128: thread covers j and j+HALF
#define BSTRIDE (S_DIM * D4)         // f32x4 stride between batches

#define LOG2_THETA  13.287712379549449f   // log2(10000)
#define LOG2_2PI     2.651496129472319f   // log2(2*pi)
#define FREQ_RATIO   0.98217188f          // theta^(-2/D)
#define RATIO_HALF   0.01f                // theta^(-2*256/D) = theta^(-1/2)

__global__ __launch_bounds__(256) void rope_kernel(
    const f32x4* __restrict__ x,
    const int*   __restrict__ pos,
    f32x4*       __restrict__ out)
{
    int t = blockIdx.x * blockDim.x + threadIdx.x;   // 0 .. S_DIM*HALF-1
    int j = t & (HALF - 1);          // f32x4 index within first half-row
    int s = t >> 7;                  // HALF == 128 == 2^7

    float p = (float)pos[s];         // wave-uniform, L1-cached

    // First f32x4 (pairs k=2j, 2j+1); second f32x4 (pairs k=2j+256, 2j+257).
    const float coef = (-2.0f / (float)D_DIM) * LOG2_THETA;
    float fA0 = __builtin_amdgcn_exp2f(coef * (float)(2 * j) - LOG2_2PI);
    float fA1 = fA0 * FREQ_RATIO;
    float fB0 = fA0 * RATIO_HALF;
    float fB1 = fB0 * FREQ_RATIO;

    // angles in revolutions, reduced to [0,1)
    float rA0 = __builtin_amdgcn_fractf(p * fA0);
    float rA1 = __builtin_amdgcn_fractf(p * fA1);
    float rB0 = __builtin_amdgcn_fractf(p * fB0);
    float rB1 = __builtin_amdgcn_fractf(p * fB1);
    float cA0 = __builtin_amdgcn_cosf(rA0), sA0 = __builtin_amdgcn_sinf(rA0);
    float cA1 = __builtin_amdgcn_cosf(rA1), sA1 = __builtin_amdgcn_sinf(rA1);
    float cB0 = __builtin_amdgcn_cosf(rB0), sB0 = __builtin_amdgcn_sinf(rB0);
    float cB1 = __builtin_amdgcn_cosf(rB1), sB1 = __builtin_amdgcn_sinf(rB1);

    int base = s * D4 + j;           // f32x4 index, batch 0
    #pragma unroll
    for (int b = 0; b < B_DIM; ++b) {
        f32x4 vA = __builtin_nontemporal_load(&x[base]);
        f32x4 vB = __builtin_nontemporal_load(&x[base + HALF]);
        f32x4 oA, oB;
        oA.x = cA0 * vA.x - sA0 * vA.y;
        oA.y = sA0 * vA.x + cA0 * vA.y;
        oA.z = cA1 * vA.z - sA1 * vA.w;
        oA.w = sA1 * vA.z + cA1 * vA.w;
        oB.x = cB0 * vB.x - sB0 * vB.y;
        oB.y = sB0 * vB.x + cB0 * vB.y;
        oB.z = cB1 * vB.z - sB1 * vB.w;
        oB.w = sB1 * vB.z + cB1 * vB.w;
        __builtin_nontemporal_store(oA, &out[base]);
        __builtin_nontemporal_store(oB, &out[base + HALF]);
        base += BSTRIDE;
    }
}

extern "C" void kernel_launch(void* const* d_in, const int* in_sizes, int n_in,
                              void* d_out, int out_size, void* d_ws, size_t ws_size,
                              hipStream_t stream) {
    const f32x4* x   = (const f32x4*)d_in[0];
    const int*   pos = (const int*)d_in[1];
    f32x4*       out = (f32x4*)d_out;

    int threads = S_DIM * HALF;               // 524,288 threads
    int blocks  = threads / 256;              // 2,048 blocks (8 per CU)
    rope_kernel<<<blocks, 256, 0, stream>>>(x, pos, out);
}